// Round 10
// baseline (90.817 us; speedup 1.0000x reference)
//
#include <hip/hip_runtime.h>

#define S 1024
#define B 32
#define D 1024
#define NCH 32          // s-chunks
#define CH (S / NCH)    // 32 rows per block
#define RPW (CH / 4)    // 8 rows per wave
#define NPAIR (RPW / 2) // 4 pairs per wave

// ws layout (floats)
#define G_OFF    0                          // g: B*D (128 KB)
#define LOG_OFF  (G_OFF + B * D)            // logits: B*S
#define MARR_OFF (LOG_OFF + B * S)          // NCH*B
#define LARR_OFF (MARR_OFF + NCH * B)       // NCH*B
#define PACC_OFF (LARR_OFF + NCH * B)       // NCH*B*D (4 MB)

// kAg: g[b,d] = sum_e h[b,e] * W[e,d], written directly (no partials, no
// atomics, no memset). 64 blocks x 128 thr; block owns 16 d-columns, thread
// (b, dq) owns one float4 of them; h staged in LDS in 128-e chunks.
__global__ __launch_bounds__(128) void kAg(const float* __restrict__ hid,
                                           const float* __restrict__ W,
                                           float* __restrict__ ws) {
    const int tid = threadIdx.x;
    const int dc  = blockIdx.x;              // 16-col slice: d0 = dc*16
    __shared__ float h_sh[128 * 33];         // [e][b], padded (16.9 KB)
    const int b  = tid >> 2;                 // 0..31
    const int dq = tid & 3;                  // float4 within 16 cols
    const float4* W4 = (const float4*)W;
    float4 a4 = {0.f, 0.f, 0.f, 0.f};
    for (int ech = 0; ech < 8; ++ech) {
        __syncthreads();                     // protect h_sh reuse
        #pragma unroll
        for (int k = 0; k < 32; ++k)         // e = tid, b' = k: coalesced in tid
            h_sh[tid * 33 + k] = hid[k * D + ech * 128 + tid];
        __syncthreads();
        for (int e = 0; e < 128; ++e) {
            float  h = h_sh[e * 33 + b];
            float4 w = W4[(size_t)(ech * 128 + e) * (D / 4) + dc * 4 + dq];
            a4.x += h * w.x; a4.y += h * w.y; a4.z += h * w.z; a4.w += h * w.w;
        }
    }
    ((float4*)(ws + G_OFF + b * D + dc * 16))[dq] = a4;
}

// kB: flash logits + online softmax + weighted partials; enc read ONCE.
// g read directly from global (L2-hot) -- no LDS prologue, no prologue
// barrier. Fence-free; inter-dispatch barrier -> kC.
__global__ __launch_bounds__(256) void kB(const float* __restrict__ enc,
                                          float* __restrict__ ws) {
    const int tid  = threadIdx.x;
    const int lane = tid & 63;
    const int wid  = tid >> 6;
    const int c    = blockIdx.x;
    const int b    = blockIdx.y;

    const float* g = ws + G_OFF;
    float* logits = ws + LOG_OFF;
    float* marr   = ws + MARR_OFF;
    float* larr   = ws + LARR_OFF;
    float* pacc   = ws + PACC_OFF;

    __shared__ float4 sacc[4 * 256];         // 16 KB, merge only
    __shared__ float sm[4], sl[4];

    // ---- issue first two pairs of enc rows, then g loads (all overlap) ----
    const float4* encb = (const float4*)enc;
    const int row0 = c * CH + wid * RPW;
    const size_t rstride = (size_t)B * (D / 4);
    size_t base = ((size_t)row0 * B + b) * (D / 4) + lane;

    float4 cur[8], nxt[8];
    #pragma unroll
    for (int j = 0; j < 4; ++j) {
        cur[j]     = encb[base + j * 64];
        cur[4 + j] = encb[base + rstride + j * 64];
    }
    #pragma unroll
    for (int j = 0; j < 4; ++j) {
        nxt[j]     = encb[base + 2 * rstride + j * 64];
        nxt[4 + j] = encb[base + 3 * rstride + j * 64];
    }
    float4 gv[4];
    #pragma unroll
    for (int j = 0; j < 4; ++j)
        gv[j] = ((const float4*)(g + b * D))[j * 64 + lane];

    // ---- flash loop: NPAIR pairs, rotate double-buffer ----
    float m = -3.0e38f, l = 0.f;
    float4 acc[4] = {{0,0,0,0},{0,0,0,0},{0,0,0,0},{0,0,0,0}};

    #pragma unroll
    for (int p = 0; p < NPAIR; ++p) {
        float pd0 = 0.f, pd1 = 0.f;
        #pragma unroll
        for (int j = 0; j < 4; ++j) {
            pd0 += cur[j].x * gv[j].x + cur[j].y * gv[j].y +
                   cur[j].z * gv[j].z + cur[j].w * gv[j].w;
            pd1 += cur[4+j].x * gv[j].x + cur[4+j].y * gv[j].y +
                   cur[4+j].z * gv[j].z + cur[4+j].w * gv[j].w;
        }
        #pragma unroll
        for (int off = 1; off < 64; off <<= 1) {   // two independent chains
            pd0 += __shfl_xor(pd0, off, 64);
            pd1 += __shfl_xor(pd1, off, 64);
        }
        if (lane == 0) {
            logits[b * S + row0 + 2 * p]     = pd0;
            logits[b * S + row0 + 2 * p + 1] = pd1;
        }
        float mn  = fmaxf(m, pd0);
        float sc0 = __expf(m - mn);
        float pA  = __expf(pd0 - mn);
        float mn2 = fmaxf(mn, pd1);
        float sc1 = __expf(mn - mn2);
        float pB  = __expf(pd1 - mn2);
        float s01 = sc0 * sc1;
        float a0  = pA * sc1;
        l = l * s01 + a0 + pB;
        #pragma unroll
        for (int j = 0; j < 4; ++j) {
            acc[j].x = acc[j].x * s01 + a0 * cur[j].x + pB * cur[4+j].x;
            acc[j].y = acc[j].y * s01 + a0 * cur[j].y + pB * cur[4+j].y;
            acc[j].z = acc[j].z * s01 + a0 * cur[j].z + pB * cur[4+j].z;
            acc[j].w = acc[j].w * s01 + a0 * cur[j].w + pB * cur[4+j].w;
        }
        m = mn2;
        if (p + 1 < NPAIR) {
            #pragma unroll
            for (int j = 0; j < 8; ++j) cur[j] = nxt[j];
        }
        if (p + 2 < NPAIR) {
            size_t nb = base + (size_t)(2 * (p + 2)) * rstride;
            #pragma unroll
            for (int j = 0; j < 4; ++j) {
                nxt[j]     = encb[nb + j * 64];
                nxt[4 + j] = encb[nb + rstride + j * 64];
            }
        }
    }

    // ---- merge 4 waves -> block partial (m, l, acc) ----
    #pragma unroll
    for (int j = 0; j < 4; ++j) sacc[wid * 256 + j * 64 + lane] = acc[j];
    if (lane == 0) { sm[wid] = m; sl[wid] = l; }
    __syncthreads();
    float mg = fmaxf(fmaxf(sm[0], sm[1]), fmaxf(sm[2], sm[3]));
    float4 r = {0.f, 0.f, 0.f, 0.f};
    float lsum = 0.f;
    #pragma unroll
    for (int w = 0; w < 4; ++w) {
        float fw = __expf(sm[w] - mg);
        float4 a = sacc[w * 256 + wid * 64 + lane];
        r.x += a.x * fw; r.y += a.y * fw; r.z += a.z * fw; r.w += a.w * fw;
        lsum += sl[w] * fw;
    }
    ((float4*)pacc)[(size_t)(c * B + b) * (D / 4) + tid] = r;
    if (tid == 0) { marr[c * B + b] = mg; larr[c * B + b] = lsum; }
}

// kC: combine NCH partials -> reps (float4, per-chunk exp factors cached in
// LDS); normalize logits -> alpha. Grid (4, B).
__global__ __launch_bounds__(256) void kC(float* __restrict__ out,
                                          const float* __restrict__ ws) {
    const int tid = threadIdx.x;
    const int q   = blockIdx.x;
    const int b   = blockIdx.y;
    const float* logits = ws + LOG_OFF;
    const float* marr   = ws + MARR_OFF;
    const float* larr   = ws + LARR_OFF;
    const float* pacc   = ws + PACC_OFF;

    __shared__ float shm[NCH], shl[NCH], shf[NCH];
    if (tid < NCH) { shm[tid] = marr[tid * B + b]; shl[tid] = larr[tid * B + b]; }
    __syncthreads();
    float mg = -3.0e38f;
    #pragma unroll
    for (int cc = 0; cc < NCH; ++cc) mg = fmaxf(mg, shm[cc]);
    if (tid < NCH) shf[tid] = __expf(shm[tid] - mg);
    __syncthreads();
    float lg = 0.f;
    #pragma unroll
    for (int cc = 0; cc < NCH; ++cc) lg += shl[cc] * shf[cc];
    const float inv = 1.f / lg;

    if (tid < 64) {            // reps quarter: 64 float4 = 256 floats of d
        const int d4 = q * 64 + tid;
        float4 racc = {0.f, 0.f, 0.f, 0.f};
        #pragma unroll 4
        for (int cc = 0; cc < NCH; ++cc) {
            float  fc = shf[cc];
            float4 v  = ((const float4*)pacc)[(size_t)(cc * B + b) * (D / 4) + d4];
            racc.x += v.x * fc; racc.y += v.y * fc;
            racc.z += v.z * fc; racc.w += v.w * fc;
        }
        float4 rep = {racc.x * inv, racc.y * inv, racc.z * inv, racc.w * inv};
        ((float4*)out)[b * (D / 4) + d4] = rep;                    // reps [B,1,D]
    }
    const int s = q * 256 + tid;
    out[B * D + b * S + s] = __expf(logits[b * S + s] - mg) * inv; // alpha [B,1,S]
}

extern "C" void kernel_launch(void* const* d_in, const int* in_sizes, int n_in,
                              void* d_out, int out_size, void* d_ws, size_t ws_size,
                              hipStream_t stream) {
    const float* hid = (const float*)d_in[0];  // (2,B,H) flat == h[B, D]
    const float* enc = (const float*)d_in[1];  // (S,B,D)
    const float* W   = (const float*)d_in[2];  // (D,D)
    // d_in[3] = bias: per-b constant in logits -> cancels in softmax.

    float* out = (float*)d_out;
    float* ws  = (float*)d_ws;

    kAg<<<dim3(64), 128, 0, stream>>>(hid, W, ws);
    kB<<<dim3(NCH, B), 256, 0, stream>>>(enc, ws);
    kC<<<dim3(4, B), 256, 0, stream>>>(out, ws);
}

// Round 11
// 41.532 us; speedup vs baseline: 2.1867x; 2.1867x over previous
//
#include <hip/hip_runtime.h>

#define S 1024
#define B 32
#define D 1024
#define NCH 32          // s-chunks
#define CH (S / NCH)    // 32 rows per block
#define RPW (CH / 4)    // 8 rows per wave
#define NPAIR (RPW / 2) // 4 pairs per wave
#define ECH 8           // e-chunks in kG
#define EC 128          // e per chunk

// ws layout (floats)
#define PG_OFF   0                          // pg: ECH*B*D (1 MB)
#define LOG_OFF  (PG_OFF + ECH * B * D)     // logits: B*S
#define MARR_OFF (LOG_OFF + B * S)          // NCH*B
#define LARR_OFF (MARR_OFF + NCH * B)       // NCH*B
#define PACC_OFF (LARR_OFF + NCH * B)       // NCH*B*D (4 MB)

// kG: pg[z][b][d] = sum_{e in chunk z} h[b,e] * W[e,d].
// Grid (D/256, B, ECH) = 1024 blocks -> 4/CU, 16 waves/CU (TLP fixes the
// latency-bound kA of R6-R10). W re-read 32x but L2/L3-hot (4 MB);
// hrow[e] is wave-uniform -> scalar broadcast; W loads stride-1 coalesced.
__global__ __launch_bounds__(256) void kG(const float* __restrict__ hid,
                                          const float* __restrict__ W,
                                          float* __restrict__ ws) {
    const int d  = blockIdx.x * 256 + threadIdx.x;
    const int b  = blockIdx.y;
    const int e0 = blockIdx.z * EC;
    const float* __restrict__ hrow = hid + b * D;
    float acc = 0.f;
    #pragma unroll 8
    for (int e = e0; e < e0 + EC; ++e)
        acc = fmaf(hrow[e], W[(size_t)e * D + d], acc);
    ws[PG_OFF + ((size_t)blockIdx.z * B + b) * D + d] = acc;
}

// kB: flash logits + online softmax + weighted partials; enc read ONCE
// (L3-resident across replays). Prologue: issue first TWO row-pairs of enc
// loads, THEN pg-reduce -> g_sh (single barrier). Fence-free.
__global__ __launch_bounds__(256) void kB(const float* __restrict__ enc,
                                          float* __restrict__ ws) {
    const int tid  = threadIdx.x;
    const int lane = tid & 63;
    const int wid  = tid >> 6;
    const int c    = blockIdx.x;
    const int b    = blockIdx.y;

    float* pg     = ws + PG_OFF;
    float* logits = ws + LOG_OFF;
    float* marr   = ws + MARR_OFF;
    float* larr   = ws + LARR_OFF;
    float* pacc   = ws + PACC_OFF;

    __shared__ float4 g_sh[256];             // 4 KB, read-only after barrier
    __shared__ float4 sacc[4 * 256];         // 16 KB, merge only
    __shared__ float sm[4], sl[4];

    // ---- issue first two pairs of enc rows (in flight during pg reduce) ----
    const float4* encb = (const float4*)enc;
    const int row0 = c * CH + wid * RPW;
    const size_t rstride = (size_t)B * (D / 4);
    size_t base = ((size_t)row0 * B + b) * (D / 4) + lane;

    float4 cur[8], nxt[8];
    #pragma unroll
    for (int j = 0; j < 4; ++j) {
        cur[j]     = encb[base + j * 64];
        cur[4 + j] = encb[base + rstride + j * 64];
    }
    #pragma unroll
    for (int j = 0; j < 4; ++j) {
        nxt[j]     = encb[base + 2 * rstride + j * 64];
        nxt[4 + j] = encb[base + 3 * rstride + j * 64];
    }

    // ---- g[b] = sum over 8 pg slices (L2-resident); single barrier ----
    {
        float4 s4 = {0.f, 0.f, 0.f, 0.f};
        #pragma unroll
        for (int ec = 0; ec < ECH; ++ec) {
            float4 v = ((const float4*)(pg + (size_t)(ec * B + b) * D))[tid];
            s4.x += v.x; s4.y += v.y; s4.z += v.z; s4.w += v.w;
        }
        g_sh[tid] = s4;
    }
    __syncthreads();
    float4 gv[4];
    #pragma unroll
    for (int j = 0; j < 4; ++j) gv[j] = g_sh[j * 64 + lane];

    // ---- flash loop: NPAIR pairs, rotate double-buffer ----
    float m = -3.0e38f, l = 0.f;
    float4 acc[4] = {{0,0,0,0},{0,0,0,0},{0,0,0,0},{0,0,0,0}};

    #pragma unroll
    for (int p = 0; p < NPAIR; ++p) {
        float pd0 = 0.f, pd1 = 0.f;
        #pragma unroll
        for (int j = 0; j < 4; ++j) {
            pd0 += cur[j].x * gv[j].x + cur[j].y * gv[j].y +
                   cur[j].z * gv[j].z + cur[j].w * gv[j].w;
            pd1 += cur[4+j].x * gv[j].x + cur[4+j].y * gv[j].y +
                   cur[4+j].z * gv[j].z + cur[4+j].w * gv[j].w;
        }
        #pragma unroll
        for (int off = 1; off < 64; off <<= 1) {   // two independent chains
            pd0 += __shfl_xor(pd0, off, 64);
            pd1 += __shfl_xor(pd1, off, 64);
        }
        if (lane == 0) {
            logits[b * S + row0 + 2 * p]     = pd0;
            logits[b * S + row0 + 2 * p + 1] = pd1;
        }
        float mn  = fmaxf(m, pd0);
        float sc0 = __expf(m - mn);
        float pA  = __expf(pd0 - mn);
        float mn2 = fmaxf(mn, pd1);
        float sc1 = __expf(mn - mn2);
        float pB  = __expf(pd1 - mn2);
        float s01 = sc0 * sc1;
        float a0  = pA * sc1;
        l = l * s01 + a0 + pB;
        #pragma unroll
        for (int j = 0; j < 4; ++j) {
            acc[j].x = acc[j].x * s01 + a0 * cur[j].x + pB * cur[4+j].x;
            acc[j].y = acc[j].y * s01 + a0 * cur[j].y + pB * cur[4+j].y;
            acc[j].z = acc[j].z * s01 + a0 * cur[j].z + pB * cur[4+j].z;
            acc[j].w = acc[j].w * s01 + a0 * cur[j].w + pB * cur[4+j].w;
        }
        m = mn2;
        if (p + 1 < NPAIR) {
            #pragma unroll
            for (int j = 0; j < 8; ++j) cur[j] = nxt[j];
        }
        if (p + 2 < NPAIR) {
            size_t nb = base + (size_t)(2 * (p + 2)) * rstride;
            #pragma unroll
            for (int j = 0; j < 4; ++j) {
                nxt[j]     = encb[nb + j * 64];
                nxt[4 + j] = encb[nb + rstride + j * 64];
            }
        }
    }

    // ---- merge 4 waves -> block partial (m, l, acc) ----
    #pragma unroll
    for (int j = 0; j < 4; ++j) sacc[wid * 256 + j * 64 + lane] = acc[j];
    if (lane == 0) { sm[wid] = m; sl[wid] = l; }
    __syncthreads();
    float mg = fmaxf(fmaxf(sm[0], sm[1]), fmaxf(sm[2], sm[3]));
    float4 r = {0.f, 0.f, 0.f, 0.f};
    float lsum = 0.f;
    #pragma unroll
    for (int w = 0; w < 4; ++w) {
        float fw = __expf(sm[w] - mg);
        float4 a = sacc[w * 256 + wid * 64 + lane];
        r.x += a.x * fw; r.y += a.y * fw; r.z += a.z * fw; r.w += a.w * fw;
        lsum += sl[w] * fw;
    }
    ((float4*)pacc)[(size_t)(c * B + b) * (D / 4) + tid] = r;
    if (tid == 0) { marr[c * B + b] = mg; larr[c * B + b] = lsum; }
}

// kC: combine NCH partials -> reps (float4, per-chunk exp factors cached in
// LDS); normalize logits -> alpha. Grid (4, B).
__global__ __launch_bounds__(256) void kC(float* __restrict__ out,
                                          const float* __restrict__ ws) {
    const int tid = threadIdx.x;
    const int q   = blockIdx.x;
    const int b   = blockIdx.y;
    const float* logits = ws + LOG_OFF;
    const float* marr   = ws + MARR_OFF;
    const float* larr   = ws + LARR_OFF;
    const float* pacc   = ws + PACC_OFF;

    __shared__ float shm[NCH], shl[NCH], shf[NCH];
    if (tid < NCH) { shm[tid] = marr[tid * B + b]; shl[tid] = larr[tid * B + b]; }
    __syncthreads();
    float mg = -3.0e38f;
    #pragma unroll
    for (int cc = 0; cc < NCH; ++cc) mg = fmaxf(mg, shm[cc]);
    if (tid < NCH) shf[tid] = __expf(shm[tid] - mg);
    __syncthreads();
    float lg = 0.f;
    #pragma unroll
    for (int cc = 0; cc < NCH; ++cc) lg += shl[cc] * shf[cc];
    const float inv = 1.f / lg;

    if (tid < 64) {            // reps quarter: 64 float4 = 256 floats of d
        const int d4 = q * 64 + tid;
        float4 racc = {0.f, 0.f, 0.f, 0.f};
        #pragma unroll 4
        for (int cc = 0; cc < NCH; ++cc) {
            float  fc = shf[cc];
            float4 v  = ((const float4*)pacc)[(size_t)(cc * B + b) * (D / 4) + d4];
            racc.x += v.x * fc; racc.y += v.y * fc;
            racc.z += v.z * fc; racc.w += v.w * fc;
        }
        float4 rep = {racc.x * inv, racc.y * inv, racc.z * inv, racc.w * inv};
        ((float4*)out)[b * (D / 4) + d4] = rep;                    // reps [B,1,D]
    }
    const int s = q * 256 + tid;
    out[B * D + b * S + s] = __expf(logits[b * S + s] - mg) * inv; // alpha [B,1,S]
}

extern "C" void kernel_launch(void* const* d_in, const int* in_sizes, int n_in,
                              void* d_out, int out_size, void* d_ws, size_t ws_size,
                              hipStream_t stream) {
    const float* hid = (const float*)d_in[0];  // (2,B,H) flat == h[B, D]
    const float* enc = (const float*)d_in[1];  // (S,B,D)
    const float* W   = (const float*)d_in[2];  // (D,D)
    // d_in[3] = bias: per-b constant in logits -> cancels in softmax.

    float* out = (float*)d_out;
    float* ws  = (float*)d_ws;

    kG<<<dim3(D / 256, B, ECH), 256, 0, stream>>>(hid, W, ws);
    kB<<<dim3(NCH, B), 256, 0, stream>>>(enc, ws);
    kC<<<dim3(4, B), 256, 0, stream>>>(out, ws);
}